// Round 2
// baseline (571.436 us; speedup 1.0000x reference)
//
#include <hip/hip_runtime.h>
#include <hip/hip_bf16.h>

#define N_NODES 50000
#define N_EDGES 600000
#define HID 128
#define HEADS 8
#define OUTC 16
#define NEG_SLOPE 0.2f
#define BN_EPS 1e-5f

typedef __attribute__((ext_vector_type(8))) short short8;
typedef __attribute__((ext_vector_type(4))) float floatx4;

// ---------------- CSR build ----------------
__global__ void k_hist(const int* __restrict__ dst, int* __restrict__ deg, int e) {
    int i = blockIdx.x * 256 + threadIdx.x;
    if (i < e) atomicAdd(&deg[dst[i]], 1);
}

__global__ void k_scan1(const int* __restrict__ deg, int* __restrict__ incl,
                        int* __restrict__ partials, int n) {
    __shared__ int sh[512];
    int i = blockIdx.x * 512 + threadIdx.x;
    int v = (i < n) ? deg[i] : 0;
    sh[threadIdx.x] = v;
    __syncthreads();
    for (int off = 1; off < 512; off <<= 1) {
        int t = (threadIdx.x >= off) ? sh[threadIdx.x - off] : 0;
        __syncthreads();
        sh[threadIdx.x] += t;
        __syncthreads();
    }
    if (i < n) incl[i] = sh[threadIdx.x];
    if (threadIdx.x == 511) partials[blockIdx.x] = sh[511];
}

__global__ void k_scan2(int* __restrict__ partials, int nb) {
    __shared__ int sh[128];
    int v = (threadIdx.x < nb) ? partials[threadIdx.x] : 0;
    sh[threadIdx.x] = v;
    __syncthreads();
    for (int off = 1; off < 128; off <<= 1) {
        int t = (threadIdx.x >= off) ? sh[threadIdx.x - off] : 0;
        __syncthreads();
        sh[threadIdx.x] += t;
        __syncthreads();
    }
    if (threadIdx.x < nb) partials[threadIdx.x] = sh[threadIdx.x] - v;  // exclusive
}

__global__ void k_scan3(const int* __restrict__ deg, const int* __restrict__ incl,
                        const int* __restrict__ partials, int* __restrict__ row_ptr,
                        int* __restrict__ cursor, int n, int e_total) {
    int i = blockIdx.x * 512 + threadIdx.x;
    if (i < n) {
        int rp = incl[i] - deg[i] + partials[blockIdx.x];
        row_ptr[i] = rp;
        cursor[i] = rp;
    }
    if (i == 0) row_ptr[n] = e_total;
}

__global__ void k_scatter(const int* __restrict__ src, const int* __restrict__ dst,
                          int* __restrict__ cursor, int* __restrict__ col_src, int e) {
    int i = blockIdx.x * 256 + threadIdx.x;
    if (i < e) {
        int d = dst[i];
        int p = atomicAdd(&cursor[d], 1);
        col_src[p] = src[i];
    }
}

// ---------------- W fp32 -> bf16 transpose (Wt[l][n][k] = W[l][k][n]) ----------------
__global__ void k_wt(const float* __restrict__ W, __hip_bfloat16* __restrict__ Wt) {
    int i = blockIdx.x * 256 + threadIdx.x;   // 3*16384 total
    if (i >= 3 * 16384) return;
    int l = i >> 14, r = i & 16383, n = r >> 7, k = r & 127;
    Wt[i] = __float2bfloat16(W[l * 16384 + k * 128 + n]);
}

// ---------------- x fp32 -> bf16 ----------------
__global__ void k_x2b(const float* __restrict__ x, __hip_bfloat16* __restrict__ xb, int total) {
    int i = blockIdx.x * 256 + threadIdx.x;
    if (i < total) xb[i] = __float2bfloat16(x[i]);
}

// ---------------- GEMM: H(fp32) = Xb(bf16) @ W(bf16), fp32 accum ----------------
__global__ __launch_bounds__(256) void k_gemm(const __hip_bfloat16* __restrict__ X,
                                              const __hip_bfloat16* __restrict__ Wt,
                                              float* __restrict__ H, int n_nodes) {
    int wave = threadIdx.x >> 6, lane = threadIdx.x & 63;
    int row0 = blockIdx.x * 64 + wave * 16;
    int m_lane = lane & 15, kq = lane >> 4;
    floatx4 acc[8] = {};
    const short* Xs = (const short*)X;
    const short* Ws = (const short*)Wt;
    int r = row0 + m_lane;
    int rr = (r < n_nodes) ? r : 0;
    for (int c = 0; c < 4; c++) {
        short8 a = *(const short8*)(Xs + rr * 128 + c * 32 + kq * 8);
        for (int t = 0; t < 8; t++) {
            short8 b = *(const short8*)(Ws + (t * 16 + m_lane) * 128 + c * 32 + kq * 8);
            acc[t] = __builtin_amdgcn_mfma_f32_16x16x32_bf16(a, b, acc[t], 0, 0, 0);
        }
    }
    for (int t = 0; t < 8; t++)
        for (int reg = 0; reg < 4; reg++) {
            int m = kq * 4 + reg;
            int rrow = row0 + m;
            if (rrow < n_nodes) H[rrow * 128 + t * 16 + m_lane] = acc[t][reg];
        }
}

// ---------------- per-(node,head) attention logits ----------------
__global__ void k_alpha(const float* __restrict__ H,
                        const float* __restrict__ asrc,
                        const float* __restrict__ adst,
                        float* __restrict__ alpha_s, float* __restrict__ alpha_d, int total) {
    int i = blockIdx.x * 256 + threadIdx.x;   // n*8+h
    if (i >= total) return;
    int h = i & 7, n = i >> 3;
    const float* hp = H + n * 128 + h * 16;
    float s = 0.f, d = 0.f;
#pragma unroll
    for (int j = 0; j < 16; j++) {
        float v = hp[j];
        s += v * asrc[h * 16 + j];
        d += v * adst[h * 16 + j];
    }
    alpha_s[i] = s;
    alpha_d[i] = d;
}

// ---------------- segment softmax + weighted aggregation ----------------
__global__ __launch_bounds__(256) void k_agg(const int* __restrict__ row_ptr,
                                             const int* __restrict__ col_src,
                                             const float* __restrict__ alpha_s,
                                             const float* __restrict__ alpha_d,
                                             const float* __restrict__ H,
                                             const float* __restrict__ bias,
                                             float* __restrict__ out, int total) {
    int i = blockIdx.x * 256 + threadIdx.x;   // n*8+h
    if (i >= total) return;
    int h = i & 7, n = i >> 3;
    int p0 = row_ptr[n], p1 = row_ptr[n + 1];
    float ad = alpha_d[i];
    float m = -1e30f;
    for (int p = p0; p < p1; p++) {
        int s = col_src[p];
        float e = alpha_s[s * 8 + h] + ad;
        e = (e > 0.f) ? e : NEG_SLOPE * e;
        m = fmaxf(m, e);
    }
    float z = 0.f;
    float acc[16];
#pragma unroll
    for (int c = 0; c < 16; c++) acc[c] = 0.f;
    for (int p = p0; p < p1; p++) {
        int s = col_src[p];
        float e = alpha_s[s * 8 + h] + ad;
        e = (e > 0.f) ? e : NEG_SLOPE * e;
        float w = __expf(e - m);
        z += w;
        const float* hp = H + s * 128 + h * 16;
#pragma unroll
        for (int j = 0; j < 16; j++) acc[j] += w * hp[j];
    }
    float inv = 1.0f / (z + 1e-16f);
    float* op = out + n * 128 + h * 16;
#pragma unroll
    for (int c = 0; c < 16; c++)
        op[c] = acc[c] * inv + bias[h * 16 + c];
}

// ---------------- BN stats (sum, sumsq per channel) ----------------
__global__ void k_bnstats(const float* __restrict__ x, float* __restrict__ stats, int n_nodes) {
    int t = blockIdx.x * blockDim.x + threadIdx.x;
    int c = t & 127;
    int g = t >> 7;
    int stride = (gridDim.x * blockDim.x) >> 7;
    float s = 0.f, q = 0.f;
    for (int n = g; n < n_nodes; n += stride) {
        float v = x[n * 128 + c];
        s += v;
        q += v * v;
    }
    atomicAdd(&stats[c], s);
    atomicAdd(&stats[128 + c], q);
}

// ---------------- BN apply + ELU; write fp32 (final) or bf16 (next layer input) -------
__global__ void k_bnapply(const float* __restrict__ x, const float* __restrict__ stats,
                          const float* __restrict__ gamma, const float* __restrict__ beta,
                          float* __restrict__ outf, __hip_bfloat16* __restrict__ outb,
                          int n_nodes) {
    int i = blockIdx.x * 256 + threadIdx.x;   // each handles 4 channels
    if (i >= n_nodes * 32) return;
    float4 v = *(const float4*)(x + (size_t)i * 4);
    int c0 = (i * 4) & 127;
    float r[4] = {v.x, v.y, v.z, v.w};
    float invN = 1.0f / (float)N_NODES;
#pragma unroll
    for (int j = 0; j < 4; j++) {
        int c = c0 + j;
        float mu = stats[c] * invN;
        float var = stats[128 + c] * invN - mu * mu;
        float sc = rsqrtf(var + BN_EPS) * gamma[c];
        float val = (r[j] - mu) * sc + beta[c];
        val = (val > 0.f) ? val : (__expf(val) - 1.0f);
        r[j] = val;
    }
    if (outf) {
        *(float4*)(outf + (size_t)i * 4) = make_float4(r[0], r[1], r[2], r[3]);
    } else {
        __hip_bfloat16* op = outb + (size_t)i * 4;
        op[0] = __float2bfloat16(r[0]);
        op[1] = __float2bfloat16(r[1]);
        op[2] = __float2bfloat16(r[2]);
        op[3] = __float2bfloat16(r[3]);
    }
}

extern "C" void kernel_launch(void* const* d_in, const int* in_sizes, int n_in,
                              void* d_out, int out_size, void* d_ws, size_t ws_size,
                              hipStream_t stream) {
    const float* x_in   = (const float*)d_in[0];
    const int*   eidx   = (const int*)d_in[1];
    const float* W      = (const float*)d_in[2];
    const float* attsrc = (const float*)d_in[3];
    const float* attdst = (const float*)d_in[4];
    const float* bias   = (const float*)d_in[5];
    const float* gamma  = (const float*)d_in[6];
    const float* beta   = (const float*)d_in[7];
    float* out = (float*)d_out;

    const int N = N_NODES, E = N_EDGES;
    const int* src = eidx;
    const int* dst = eidx + E;

    // workspace carve-up
    char* base = (char*)d_ws;
    size_t off = 0;
    auto carve = [&](size_t bytes) -> char* {
        char* p = base + off;
        off += (bytes + 255) & ~(size_t)255;
        return p;
    };
    float*          H   = (float*)carve((size_t)N * HID * 4);           // fp32 features
    __hip_bfloat16* XB  = (__hip_bfloat16*)carve((size_t)N * HID * 2);  // bf16 GEMM input
    float*          XN  = (float*)carve((size_t)N * HID * 4);           // agg output
    float*          AS  = (float*)carve((size_t)N * HEADS * 4);
    float*          AD  = (float*)carve((size_t)N * HEADS * 4);
    __hip_bfloat16* WT  = (__hip_bfloat16*)carve((size_t)3 * HID * HID * 2);
    int*            DEG = (int*)carve((size_t)N * 4);
    int*            INC = (int*)carve((size_t)N * 4);
    int*            RP  = (int*)carve((size_t)(N + 1) * 4);
    int*            CUR = (int*)carve((size_t)N * 4);
    int*            PRT = (int*)carve(1024 * 4);
    int*            COL = (int*)carve((size_t)E * 4);
    float*          STA = (float*)carve(256 * 4);

    const int NB_E  = (E + 255) / 256;
    const int NB_SC = (N + 511) / 512;   // 98

    // ---- CSR build (once; reused by all 3 layers) ----
    hipMemsetAsync(DEG, 0, (size_t)N * 4, stream);
    k_hist<<<NB_E, 256, 0, stream>>>(dst, DEG, E);
    k_scan1<<<NB_SC, 512, 0, stream>>>(DEG, INC, PRT, N);
    k_scan2<<<1, 128, 0, stream>>>(PRT, NB_SC);
    k_scan3<<<NB_SC, 512, 0, stream>>>(DEG, INC, PRT, RP, CUR, N, E);
    k_scatter<<<NB_E, 256, 0, stream>>>(src, dst, CUR, COL, E);

    // ---- weights to bf16 (transposed), x to bf16 ----
    k_wt<<<(3 * 16384 + 255) / 256, 256, 0, stream>>>(W, WT);
    k_x2b<<<(N * HID + 255) / 256, 256, 0, stream>>>(x_in, XB, N * HID);

    const int total_nh = N * HEADS;
    const int NB_NH = (total_nh + 255) / 256;

    for (int l = 0; l < 3; l++) {
        k_gemm<<<(N + 63) / 64, 256, 0, stream>>>(XB, WT + l * 16384, H, N);
        k_alpha<<<NB_NH, 256, 0, stream>>>(H, attsrc + l * 128, attdst + l * 128, AS, AD, total_nh);
        k_agg<<<NB_NH, 256, 0, stream>>>(RP, COL, AS, AD, H, bias + l * 128, XN, total_nh);
        hipMemsetAsync(STA, 0, 256 * 4, stream);
        k_bnstats<<<256, 256, 0, stream>>>(XN, STA, N);
        if (l == 2)
            k_bnapply<<<(N * 32 + 255) / 256, 256, 0, stream>>>(XN, STA, gamma + l * 128, beta + l * 128, out, nullptr, N);
        else
            k_bnapply<<<(N * 32 + 255) / 256, 256, 0, stream>>>(XN, STA, gamma + l * 128, beta + l * 128, nullptr, XB, N);
    }
}

// Round 3
// 497.843 us; speedup vs baseline: 1.1478x; 1.1478x over previous
//
#include <hip/hip_runtime.h>
#include <hip/hip_bf16.h>

#define N_NODES 50000
#define N_EDGES 600000
#define HID 128
#define HEADS 8
#define OUTC 16
#define NEG_SLOPE 0.2f
#define BN_EPS 1e-5f

typedef __attribute__((ext_vector_type(8))) short short8;
typedef __attribute__((ext_vector_type(4))) float floatx4;

__device__ __forceinline__ float bf_lo(unsigned int v) { return __uint_as_float(v << 16); }
__device__ __forceinline__ float bf_hi(unsigned int v) { return __uint_as_float(v & 0xffff0000u); }

// ---------------- CSR build ----------------
__global__ void k_hist(const int* __restrict__ dst, int* __restrict__ deg, int e) {
    int i = blockIdx.x * 256 + threadIdx.x;
    if (i < e) atomicAdd(&deg[dst[i]], 1);
}

__global__ void k_scan1(const int* __restrict__ deg, int* __restrict__ incl,
                        int* __restrict__ partials, int n) {
    __shared__ int sh[512];
    int i = blockIdx.x * 512 + threadIdx.x;
    int v = (i < n) ? deg[i] : 0;
    sh[threadIdx.x] = v;
    __syncthreads();
    for (int off = 1; off < 512; off <<= 1) {
        int t = (threadIdx.x >= off) ? sh[threadIdx.x - off] : 0;
        __syncthreads();
        sh[threadIdx.x] += t;
        __syncthreads();
    }
    if (i < n) incl[i] = sh[threadIdx.x];
    if (threadIdx.x == 511) partials[blockIdx.x] = sh[511];
}

__global__ void k_scan2(int* __restrict__ partials, int nb) {
    __shared__ int sh[128];
    int v = (threadIdx.x < nb) ? partials[threadIdx.x] : 0;
    sh[threadIdx.x] = v;
    __syncthreads();
    for (int off = 1; off < 128; off <<= 1) {
        int t = (threadIdx.x >= off) ? sh[threadIdx.x - off] : 0;
        __syncthreads();
        sh[threadIdx.x] += t;
        __syncthreads();
    }
    if (threadIdx.x < nb) partials[threadIdx.x] = sh[threadIdx.x] - v;  // exclusive
}

__global__ void k_scan3(const int* __restrict__ deg, const int* __restrict__ incl,
                        const int* __restrict__ partials, int* __restrict__ row_ptr,
                        int* __restrict__ cursor, int n, int e_total) {
    int i = blockIdx.x * 512 + threadIdx.x;
    if (i < n) {
        int rp = incl[i] - deg[i] + partials[blockIdx.x];
        row_ptr[i] = rp;
        cursor[i] = rp;
    }
    if (i == 0) row_ptr[n] = e_total;
}

__global__ void k_scatter(const int* __restrict__ src, const int* __restrict__ dst,
                          int* __restrict__ cursor, int* __restrict__ col_src, int e) {
    int i = blockIdx.x * 256 + threadIdx.x;
    if (i < e) {
        int d = dst[i];
        int p = atomicAdd(&cursor[d], 1);
        col_src[p] = src[i];
    }
}

// ---------------- W fp32 -> bf16 transpose (Wt[l][n][k] = W[l][k][n]) ----------------
__global__ void k_wt(const float* __restrict__ W, __hip_bfloat16* __restrict__ Wt) {
    int i = blockIdx.x * 256 + threadIdx.x;   // 3*16384 total
    if (i >= 3 * 16384) return;
    int l = i >> 14, r = i & 16383, n = r >> 7, k = r & 127;
    Wt[i] = __float2bfloat16(W[l * 16384 + k * 128 + n]);
}

// ---------------- x fp32 -> bf16 ----------------
__global__ void k_x2b(const float* __restrict__ x, __hip_bfloat16* __restrict__ xb, int total) {
    int i = blockIdx.x * 256 + threadIdx.x;
    if (i < total) xb[i] = __float2bfloat16(x[i]);
}

// ---- GEMM + fused alpha: Hb(bf16) = Xb@W; AS/AD from fp32 accumulators ----
__global__ __launch_bounds__(256) void k_gemm(const __hip_bfloat16* __restrict__ X,
                                              const __hip_bfloat16* __restrict__ Wt,
                                              const float* __restrict__ asrc,
                                              const float* __restrict__ adst,
                                              __hip_bfloat16* __restrict__ Hb,
                                              float* __restrict__ AS, float* __restrict__ AD,
                                              int n_nodes) {
    int wave = threadIdx.x >> 6, lane = threadIdx.x & 63;
    int row0 = blockIdx.x * 64 + wave * 16;
    int m_lane = lane & 15, kq = lane >> 4;
    floatx4 acc[8] = {};
    const short* Xs = (const short*)X;
    const short* Ws = (const short*)Wt;
    int r = row0 + m_lane;
    int rr = (r < n_nodes) ? r : 0;
    for (int c = 0; c < 4; c++) {
        short8 a = *(const short8*)(Xs + rr * 128 + c * 32 + kq * 8);
        for (int t = 0; t < 8; t++) {
            short8 b = *(const short8*)(Ws + (t * 16 + m_lane) * 128 + c * 32 + kq * 8);
            acc[t] = __builtin_amdgcn_mfma_f32_16x16x32_bf16(a, b, acc[t], 0, 0, 0);
        }
    }
    // per-head att vectors: head t, channel m_lane
    float as_l[8], ad_l[8];
#pragma unroll
    for (int t = 0; t < 8; t++) {
        as_l[t] = asrc[t * 16 + m_lane];
        ad_l[t] = adst[t * 16 + m_lane];
    }
#pragma unroll
    for (int reg = 0; reg < 4; reg++) {
        int row = row0 + kq * 4 + reg;
        bool ok = row < n_nodes;
#pragma unroll
        for (int t = 0; t < 8; t++) {
            float v = acc[t][reg];
            if (ok) Hb[row * 128 + t * 16 + m_lane] = __float2bfloat16(v);
            float ps = v * as_l[t], pd = v * ad_l[t];
#pragma unroll
            for (int off = 1; off < 16; off <<= 1) {
                ps += __shfl_xor(ps, off, 64);
                pd += __shfl_xor(pd, off, 64);
            }
            if (ok && m_lane == 0) {
                AS[row * 8 + t] = ps;
                AD[row * 8 + t] = pd;
            }
        }
    }
}

// ---- segment softmax + aggregation: one WAVE per node; lane = e_local*8 + head ----
__global__ __launch_bounds__(256) void k_agg(const int* __restrict__ RP,
                                             const int* __restrict__ COL,
                                             const float* __restrict__ AS,
                                             const float* __restrict__ AD,
                                             const __hip_bfloat16* __restrict__ Hb,
                                             const float* __restrict__ bias,
                                             float* __restrict__ out, int n_nodes) {
    int wave = threadIdx.x >> 6, lane = threadIdx.x & 63;
    int n = blockIdx.x * 4 + wave;
    if (n >= n_nodes) return;
    int e_l = lane >> 3, h = lane & 7;
    int p0 = RP[n], p1 = RP[n + 1];
    float ad = AD[n * 8 + h];
    float m = -1e30f, z = 0.f;
    float acc[16];
#pragma unroll
    for (int c = 0; c < 16; c++) acc[c] = 0.f;
    const unsigned short* Hu = (const unsigned short*)Hb;
    for (int p = p0 + e_l; p < p1; p += 8) {
        int s = COL[p];
        float e = AS[s * 8 + h] + ad;
        e = (e > 0.f) ? e : NEG_SLOPE * e;
        float mn = fmaxf(m, e);
        float corr = __expf(m - mn);
        float w = __expf(e - mn);
        m = mn;
        z = z * corr + w;
        const uint4* hp = (const uint4*)(Hu + s * 128 + h * 16);
        uint4 h0 = hp[0];
        uint4 h1 = hp[1];
        unsigned int ww[8] = {h0.x, h0.y, h0.z, h0.w, h1.x, h1.y, h1.z, h1.w};
#pragma unroll
        for (int j = 0; j < 8; j++) {
            acc[2 * j]     = acc[2 * j]     * corr + w * bf_lo(ww[j]);
            acc[2 * j + 1] = acc[2 * j + 1] * corr + w * bf_hi(ww[j]);
        }
    }
    // combine the 8 edge-lanes (lane bits 3..5), exact online-softmax merge
#pragma unroll
    for (int off = 8; off < 64; off <<= 1) {
        float mo = __shfl_xor(m, off, 64);
        float zo = __shfl_xor(z, off, 64);
        float mn = fmaxf(m, mo);
        float c1 = __expf(m - mn), c2 = __expf(mo - mn);
        z = z * c1 + zo * c2;
#pragma unroll
        for (int c = 0; c < 16; c++) {
            float ao = __shfl_xor(acc[c], off, 64);
            acc[c] = acc[c] * c1 + ao * c2;
        }
        m = mn;
    }
    if (e_l == 0) {
        float inv = 1.0f / (z + 1e-16f);
        float4* op = (float4*)(out + n * 128 + h * 16);
        const float* bp = bias + h * 16;
#pragma unroll
        for (int q = 0; q < 4; q++) {
            op[q] = make_float4(acc[4 * q]     * inv + bp[4 * q],
                                acc[4 * q + 1] * inv + bp[4 * q + 1],
                                acc[4 * q + 2] * inv + bp[4 * q + 2],
                                acc[4 * q + 3] * inv + bp[4 * q + 3]);
        }
    }
}

// ---------------- BN stats (sum, sumsq per channel) ----------------
__global__ void k_bnstats(const float* __restrict__ x, float* __restrict__ stats, int n_nodes) {
    int t = blockIdx.x * blockDim.x + threadIdx.x;
    int c = t & 127;
    int g = t >> 7;
    int stride = (gridDim.x * blockDim.x) >> 7;
    float s = 0.f, q = 0.f;
    for (int n = g; n < n_nodes; n += stride) {
        float v = x[n * 128 + c];
        s += v;
        q += v * v;
    }
    atomicAdd(&stats[c], s);
    atomicAdd(&stats[128 + c], q);
}

// ---------------- BN apply + ELU; write fp32 (final) or bf16 (next layer input) -------
__global__ void k_bnapply(const float* __restrict__ x, const float* __restrict__ stats,
                          const float* __restrict__ gamma, const float* __restrict__ beta,
                          float* __restrict__ outf, __hip_bfloat16* __restrict__ outb,
                          int n_nodes) {
    int i = blockIdx.x * 256 + threadIdx.x;   // each handles 4 channels
    if (i >= n_nodes * 32) return;
    float4 v = *(const float4*)(x + (size_t)i * 4);
    int c0 = (i * 4) & 127;
    float r[4] = {v.x, v.y, v.z, v.w};
    float invN = 1.0f / (float)N_NODES;
#pragma unroll
    for (int j = 0; j < 4; j++) {
        int c = c0 + j;
        float mu = stats[c] * invN;
        float var = stats[128 + c] * invN - mu * mu;
        float sc = rsqrtf(var + BN_EPS) * gamma[c];
        float val = (r[j] - mu) * sc + beta[c];
        val = (val > 0.f) ? val : (__expf(val) - 1.0f);
        r[j] = val;
    }
    if (outf) {
        *(float4*)(outf + (size_t)i * 4) = make_float4(r[0], r[1], r[2], r[3]);
    } else {
        __hip_bfloat16* op = outb + (size_t)i * 4;
        op[0] = __float2bfloat16(r[0]);
        op[1] = __float2bfloat16(r[1]);
        op[2] = __float2bfloat16(r[2]);
        op[3] = __float2bfloat16(r[3]);
    }
}

extern "C" void kernel_launch(void* const* d_in, const int* in_sizes, int n_in,
                              void* d_out, int out_size, void* d_ws, size_t ws_size,
                              hipStream_t stream) {
    const float* x_in   = (const float*)d_in[0];
    const int*   eidx   = (const int*)d_in[1];
    const float* W      = (const float*)d_in[2];
    const float* attsrc = (const float*)d_in[3];
    const float* attdst = (const float*)d_in[4];
    const float* bias   = (const float*)d_in[5];
    const float* gamma  = (const float*)d_in[6];
    const float* beta   = (const float*)d_in[7];
    float* out = (float*)d_out;

    const int N = N_NODES, E = N_EDGES;
    const int* src = eidx;
    const int* dst = eidx + E;

    // workspace carve-up
    char* base = (char*)d_ws;
    size_t off = 0;
    auto carve = [&](size_t bytes) -> char* {
        char* p = base + off;
        off += (bytes + 255) & ~(size_t)255;
        return p;
    };
    __hip_bfloat16* Hb  = (__hip_bfloat16*)carve((size_t)N * HID * 2);  // bf16 features
    __hip_bfloat16* XB  = (__hip_bfloat16*)carve((size_t)N * HID * 2);  // bf16 GEMM input
    float*          XN  = (float*)carve((size_t)N * HID * 4);           // agg output
    float*          AS  = (float*)carve((size_t)N * HEADS * 4);
    float*          AD  = (float*)carve((size_t)N * HEADS * 4);
    __hip_bfloat16* WT  = (__hip_bfloat16*)carve((size_t)3 * HID * HID * 2);
    int*            DEG = (int*)carve((size_t)N * 4);
    int*            INC = (int*)carve((size_t)N * 4);
    int*            RP  = (int*)carve((size_t)(N + 1) * 4);
    int*            CUR = (int*)carve((size_t)N * 4);
    int*            PRT = (int*)carve(1024 * 4);
    int*            COL = (int*)carve((size_t)E * 4);
    float*          STA = (float*)carve(256 * 4);

    const int NB_E  = (E + 255) / 256;
    const int NB_SC = (N + 511) / 512;   // 98

    // ---- CSR build (once; reused by all 3 layers) ----
    hipMemsetAsync(DEG, 0, (size_t)N * 4, stream);
    k_hist<<<NB_E, 256, 0, stream>>>(dst, DEG, E);
    k_scan1<<<NB_SC, 512, 0, stream>>>(DEG, INC, PRT, N);
    k_scan2<<<1, 128, 0, stream>>>(PRT, NB_SC);
    k_scan3<<<NB_SC, 512, 0, stream>>>(DEG, INC, PRT, RP, CUR, N, E);
    k_scatter<<<NB_E, 256, 0, stream>>>(src, dst, CUR, COL, E);

    // ---- weights to bf16 (transposed), x to bf16 ----
    k_wt<<<(3 * 16384 + 255) / 256, 256, 0, stream>>>(W, WT);
    k_x2b<<<(N * HID + 255) / 256, 256, 0, stream>>>(x_in, XB, N * HID);

    for (int l = 0; l < 3; l++) {
        k_gemm<<<(N + 63) / 64, 256, 0, stream>>>(XB, WT + l * 16384,
                                                  attsrc + l * 128, attdst + l * 128,
                                                  Hb, AS, AD, N);
        k_agg<<<(N + 3) / 4, 256, 0, stream>>>(RP, COL, AS, AD, Hb, bias + l * 128, XN, N);
        hipMemsetAsync(STA, 0, 256 * 4, stream);
        k_bnstats<<<256, 256, 0, stream>>>(XN, STA, N);
        if (l == 2)
            k_bnapply<<<(N * 32 + 255) / 256, 256, 0, stream>>>(XN, STA, gamma + l * 128, beta + l * 128, out, nullptr, N);
        else
            k_bnapply<<<(N * 32 + 255) / 256, 256, 0, stream>>>(XN, STA, gamma + l * 128, beta + l * 128, nullptr, XB, N);
    }
}